// Round 10
// baseline (127.332 us; speedup 1.0000x reference)
//
#include <hip/hip_runtime.h>

// Updater: B=4194304 sequential scan, 3 independent scalar recurrences
//   net' = sigmoid(10*(net + u - 0.5)), u = W*x + b, pred = x . net'
// Chunked-scan parallelization with certified warm-up (monotone map ->
// trajectories from 0 and 1 bracket the truth; dual-trajectory warm-up with
// wave-uniform early exit; geometric global backoff, rare, exact at net0).
//
// R10 = R9 with the compile fix (name collisions: bpermute addrs now
// pa1/pa2, transpose write addrs wa0/wa1/wa2). Theory unchanged:
// every prior round ran at hbm_bytes / ~2.2-2.7 TB/s; the chip does
// 6.3 TB/s with WAVE-contiguous access (instr i, lane l -> base + i*1KB
// + l*16B: 16 fully-used lines/instr) vs our per-lane gathers (64 lines
// touched/instr, 16B used each -> ~2.5x read-BW penalty). Fix:
//  - wave window (64 lanes x 16 steps x 12B = 12KB) loaded as 12
//    wave-contiguous dwordx4/lane in 4 quarters, double-buffered through
//    a per-wave LDS transpose buffer (2 x 3328B);
//  - ds_write to padded regions (QW=52 words/lane: region starts at
//    banks 20*(r mod 8)*... -> reads hit the 2-lane/bank floor),
//    each lane ds_read_b128 its 12 float4 -> fx[48] in its quarter phase.
//    All wave-private: NO __syncthreads; in-order DS pipe gives RAW.
//  - CHUNK=16, GRID=1024 = exactly 4 blocks/CU -> single round,
//    4 waves/SIMD. __launch_bounds__(256,4), ~100 VGPR, no spill.
//  - WARM=32 (R8 proved 64 is a 6.5us loss); warm via distance-2/1
//    bpermutes; boundary lanes 0,1 from per-wave wbuf.

#if __has_builtin(__builtin_amdgcn_exp2f)
#define EXP2F(v) __builtin_amdgcn_exp2f(v)
#else
#define EXP2F(v) __expf(0.6931471805599453f * (v))
#endif

namespace {
constexpr int   BTOT   = 4194304;
constexpr int   CHUNK  = 16;                  // output steps per thread
constexpr int   BLOCK  = 256;
constexpr int   BSTEPS = BLOCK * CHUNK;       // 4096 steps per block
constexpr int   WARM   = 32;                  // warm-up window (steps)
constexpr int   GRID   = BTOT / BSTEPS;       // 1024 blocks
constexpr int   QW     = 52;                  // words per lane region (48+4 pad)
constexpr float KEXP   = -14.426950408889634f; // -10 * log2(e)
constexpr float EPS    = 1e-5f;
}

// sigmoid(10*(n+u-0.5)) = rcp(1 + exp2(KEXP*n + c)), c = (KEXP*W)x + KEXP*(b-.5)
#define CVALS(X0_, X1_, X2_)                                                   \
  const float c0 = fmaf(kw00, (X0_), fmaf(kw01, (X1_), fmaf(kw02, (X2_), kb0))); \
  const float c1 = fmaf(kw10, (X0_), fmaf(kw11, (X1_), fmaf(kw12, (X2_), kb1))); \
  const float c2 = fmaf(kw20, (X0_), fmaf(kw21, (X1_), fmaf(kw22, (X2_), kb2)));

#define SIG(N, C) __builtin_amdgcn_rcpf(1.0f + EXP2F(fmaf(KEXP, (N), (C))))

#define PULL(VAL_, AD_) \
  __int_as_float(__builtin_amdgcn_ds_bpermute((AD_), __float_as_int(VAL_)))

// warm-step S_ (compile-time): s<16 -> owner lane-2 (pa2); s>=16 -> lane-1
// (pa1). Boundary: lane0 all s -> wbuf[s]; lane1 s<16 -> wbuf[s+16].
#define FETCH1(S_, XD0, XD1, XD2)                                              \
  if ((S_) < 16) {                                                             \
    XD0 = PULL(fx[3 * (S_) + 0], pa2);                                         \
    XD1 = PULL(fx[3 * (S_) + 1], pa2);                                         \
    XD2 = PULL(fx[3 * (S_) + 2], pa2);                                         \
    if (lane < 2) {                                                            \
      const float4 wv_ = wb[(S_) + (lane << 4)];                               \
      XD0 = wv_.x; XD1 = wv_.y; XD2 = wv_.z;                                   \
    }                                                                          \
  } else {                                                                     \
    XD0 = PULL(fx[3 * ((S_) - 16) + 0], pa1);                                  \
    XD1 = PULL(fx[3 * ((S_) - 16) + 1], pa1);                                  \
    XD2 = PULL(fx[3 * ((S_) - 16) + 2], pa1);                                  \
    if (lane < 1) {                                                            \
      const float4 wv_ = wb[(S_)];                                             \
      XD0 = wv_.x; XD1 = wv_.y; XD2 = wv_.z;                                   \
    }                                                                          \
  }

// dual-trajectory (bracket) step
#define DSTEP(X0_, X1_, X2_)                                                   \
  {                                                                            \
    CVALS(X0_, X1_, X2_)                                                       \
    lo0 = SIG(lo0, c0); hi0 = SIG(hi0, c0);                                    \
    lo1 = SIG(lo1, c1); hi1 = SIG(hi1, c1);                                    \
    lo2 = SIG(lo2, c2); hi2 = SIG(hi2, c2);                                    \
  }

// single-trajectory step
#define SSTEP(X0_, X1_, X2_)                                                   \
  {                                                                            \
    CVALS(X0_, X1_, X2_)                                                       \
    m0 = SIG(m0, c0); m1 = SIG(m1, c1); m2 = SIG(m2, c2);                      \
  }

// warm batch: 4 steps; fetches hoisted above the wave-uniform branch
#define WBATCH(B_)                                                             \
  {                                                                            \
    float X00,X01,X02,X10,X11,X12,X20,X21,X22,X30,X31,X32;                     \
    FETCH1(4*(B_)+0, X00, X01, X02)                                            \
    FETCH1(4*(B_)+1, X10, X11, X12)                                            \
    FETCH1(4*(B_)+2, X20, X21, X22)                                            \
    FETCH1(4*(B_)+3, X30, X31, X32)                                            \
    if (!single) {                                                             \
      DSTEP(X00, X01, X02) DSTEP(X10, X11, X12)                                \
      DSTEP(X20, X21, X22) DSTEP(X30, X31, X32)                                \
      conv = ((hi0 - lo0) < EPS) & ((hi1 - lo1) < EPS) & ((hi2 - lo2) < EPS);  \
      if (__all(conv)) {                                                       \
        m0 = 0.5f * (lo0 + hi0); m1 = 0.5f * (lo1 + hi1);                      \
        m2 = 0.5f * (lo2 + hi2);                                               \
        single = true;                                                         \
      }                                                                        \
    } else {                                                                   \
      SSTEP(X00, X01, X02) SSTEP(X10, X11, X12)                                \
      SSTEP(X20, X21, X22) SSTEP(X30, X31, X32)                                \
    }                                                                          \
  }

// main step: advance + pred (x from registers)
#define MS(P_, X0_, X1_, X2_)                                                  \
  {                                                                            \
    CVALS(X0_, X1_, X2_)                                                       \
    m0 = SIG(m0, c0); m1 = SIG(m1, c1); m2 = SIG(m2, c2);                      \
    P_ = fmaf((X0_), m0, fmaf((X1_), m1, (X2_) * m2));                         \
  }

// LDS float4 store / lane-region read
#define STW(P_, O_, V_) *reinterpret_cast<float4*>((P_) + (O_)) = (V_);
#define RDQ(P_)                                                                \
  _Pragma("unroll")                                                            \
  for (int j = 0; j < 12; ++j) {                                               \
    const float4 v = *reinterpret_cast<const float4*>((P_) + rb + 4 * j);      \
    fx[4 * j + 0] = v.x; fx[4 * j + 1] = v.y;                                  \
    fx[4 * j + 2] = v.z; fx[4 * j + 3] = v.w;                                  \
  }

__global__ __launch_bounds__(BLOCK, 4) void Updater_65395172049297_kernel(
    const float* __restrict__ x, const float* __restrict__ W,
    const float* __restrict__ bv, const float* __restrict__ n0v,
    float* __restrict__ out)
{
    __shared__ float  qbuf[BLOCK / 64][2][16 * QW];  // 4w x 2 x 3328B = 26.6KB
    __shared__ float4 wbuf[BLOCK / 64][WARM];        // 4w x 32 x 16B  =  2KB

    const float kw00 = KEXP * W[0], kw01 = KEXP * W[1], kw02 = KEXP * W[2];
    const float kw10 = KEXP * W[3], kw11 = KEXP * W[4], kw12 = KEXP * W[5];
    const float kw20 = KEXP * W[6], kw21 = KEXP * W[7], kw22 = KEXP * W[8];
    const float kb0 = KEXP * (bv[0] - 0.5f);
    const float kb1 = KEXP * (bv[1] - 0.5f);
    const float kb2 = KEXP * (bv[2] - 0.5f);
    const float n00 = n0v[0], n01 = n0v[1], n02 = n0v[2];

    const int  lane  = threadIdx.x & 63;
    const int  w     = threadIdx.x >> 6;
    const long S     = (long)blockIdx.x * BSTEPS;
    const long Wb    = S + (long)w * (64 * CHUNK);       // wave base step
    const long start = Wb + (long)lane * CHUNK;
    const int  pa1   = ((lane >= 1) ? (lane - 1) : 0) << 2;  // bpermute addrs
    const int  pa2   = ((lane >= 2) ? (lane - 2) : 0) << 2;
    const float4* wb = wbuf[w];

    // ---- boundary window load first (lanes 0..31, 1 scalar-triple each) ----
    float4 wv;
    if (lane < WARM) {
        long sstep = Wb - WARM + lane;
        if (sstep < 0) sstep = 0;        // block0/wave0 uses the special path
        const float* xp = x + 3 * sstep;
        wv = make_float4(xp[0], xp[1], xp[2], 0.0f);
    }

    // ---- wave-contiguous gather + LDS transpose -> fx[48] ----
    // wave window = 768 float4; load pattern xw[64*i + lane] = 1KB/instr.
    const float4* xw = reinterpret_cast<const float4*>(x) +
                       ((long)blockIdx.x * 3072 + (long)w * 768);
    // transpose write addrs: quarter-local g = 64i+lane -> region g/12,
    // slot g%12 -> word (g/12)*QW + (g%12)*4
    const int g0  = lane, g1 = 64 + lane, g2 = 128 + lane;
    const int wa0 = (g0 / 12) * QW + (g0 % 12) * 4;
    const int wa1 = (g1 / 12) * QW + (g1 % 12) * 4;
    const int wa2 = (g2 / 12) * QW + (g2 % 12) * 4;
    float* A  = qbuf[w][0];
    float* Bf = qbuf[w][1];
    const int myq = lane >> 4;           // which quarter holds my chunk
    const int rb  = (lane & 15) * QW;    // my region base (words)

    float fx[48];
    {
        float4 r0 = xw[g0],       r1 = xw[g1],       r2 = xw[g2];        // q0
        float4 s0 = xw[192 + g0], s1 = xw[192 + g1], s2 = xw[192 + g2];  // q1
        STW(A, wa0, r0) STW(A, wa1, r1) STW(A, wa2, r2)                  // q0->A
        if (myq == 0) { RDQ(A) }                                         // 0-15
        r0 = xw[384 + g0]; r1 = xw[384 + g1]; r2 = xw[384 + g2];         // q2
        STW(Bf, wa0, s0) STW(Bf, wa1, s1) STW(Bf, wa2, s2)               // q1->B
        if (myq == 1) { RDQ(Bf) }                                        // 16-31
        s0 = xw[576 + g0]; s1 = xw[576 + g1]; s2 = xw[576 + g2];         // q3
        STW(A, wa0, r0) STW(A, wa1, r1) STW(A, wa2, r2)                  // q2->A
        if (myq == 2) { RDQ(A) }                                         // 32-47
        STW(Bf, wa0, s0) STW(Bf, wa1, s1) STW(Bf, wa2, s2)               // q3->B
        if (myq == 3) { RDQ(Bf) }                                        // 48-63
    }

    // wave-private wbuf publish (in-order DS pipe; no __syncthreads)
    if (lane < WARM) wbuf[w][lane] = wv;

    const bool exact   = (start <= (long)WARM);   // block0/wave0 lanes 0,1,2
    const int  smin    = exact ? (int)(WARM - (int)start) : 0;
    const bool special = (blockIdx.x == 0) && (w == 0);

    float lo0, lo1, lo2, hi0, hi1, hi2;
    if (exact) { lo0 = hi0 = n00; lo1 = hi1 = n01; lo2 = hi2 = n02; }
    else       { lo0 = lo1 = lo2 = 0.0f; hi0 = hi1 = hi2 = 1.0f; }

    bool  conv = false, single = false;
    float m0 = n00, m1 = n01, m2 = n02;

    if (special) {
        // ONE wave in the grid: rolled warm-up straight from global x.
        for (int s = 0; s < WARM; ++s) {
            if (s >= smin) {
                const long as_ = start - WARM + s;   // >= 0 when s >= smin
                const float X0 = x[3 * as_], X1 = x[3 * as_ + 1], X2 = x[3 * as_ + 2];
                DSTEP(X0, X1, X2)
            }
        }
        conv = ((hi0 - lo0) < EPS) & ((hi1 - lo1) < EPS) & ((hi2 - lo2) < EPS);
        if (__all(conv)) {
            m0 = 0.5f * (lo0 + hi0); m1 = 0.5f * (lo1 + hi1); m2 = 0.5f * (lo2 + hi2);
            single = true;
        }
    } else {
        WBATCH(0) WBATCH(1) WBATCH(2) WBATCH(3)
        WBATCH(4) WBATCH(5) WBATCH(6) WBATCH(7)
    }

    if (!single) {
        // rare certified backoff: extend window 4x per attempt (global x)
        for (int at = 1; at < 10 && !conv; ++at) {
            long wl2 = (long)WARM << (2 * at);
            long bgn = start - wl2;
            bool ex2 = (bgn <= 0);
            if (ex2) bgn = 0;
            if (ex2) { lo0 = hi0 = n00; lo1 = hi1 = n01; lo2 = hi2 = n02; }
            else     { lo0 = lo1 = lo2 = 0.0f; hi0 = hi1 = hi2 = 1.0f; }
            const float4* bp = reinterpret_cast<const float4*>(x + 3 * bgn);
            const long ng = (start - bgn) >> 2;   // groups of 4 steps
            for (long q = 0; q < ng; ++q) {
                const float4 A4 = bp[3 * q], B4 = bp[3 * q + 1], C4 = bp[3 * q + 2];
                DSTEP(A4.x, A4.y, A4.z)
                DSTEP(A4.w, B4.x, B4.y)
                DSTEP(B4.z, B4.w, C4.x)
                DSTEP(C4.y, C4.z, C4.w)
            }
            conv = ex2 || (((hi0 - lo0) < EPS) & ((hi1 - lo1) < EPS) &
                           ((hi2 - lo2) < EPS));
        }
        m0 = 0.5f * (lo0 + hi0); m1 = 0.5f * (lo1 + hi1); m2 = 0.5f * (lo2 + hi2);
    }

    // ---- main chunk: 16 steps from registers, 4 float4 stores ----
    float4* op = reinterpret_cast<float4*>(out + start);
#pragma unroll
    for (int q = 0; q < 4; ++q) {
        float p0, p1, p2, p3;
        MS(p0, fx[12 * q + 0], fx[12 * q + 1],  fx[12 * q + 2]);
        MS(p1, fx[12 * q + 3], fx[12 * q + 4],  fx[12 * q + 5]);
        MS(p2, fx[12 * q + 6], fx[12 * q + 7],  fx[12 * q + 8]);
        MS(p3, fx[12 * q + 9], fx[12 * q + 10], fx[12 * q + 11]);
        op[q] = make_float4(p0, p1, p2, p3);
    }
}

extern "C" void kernel_launch(void* const* d_in, const int* in_sizes, int n_in,
                              void* d_out, int out_size, void* d_ws, size_t ws_size,
                              hipStream_t stream) {
    const float* x   = (const float*)d_in[0];   // (B,1,3)
    const float* W   = (const float*)d_in[1];   // (3,3)
    const float* bv  = (const float*)d_in[2];   // (3,)
    const float* n0v = (const float*)d_in[3];   // (3,1)
    float*       out = (float*)d_out;           // (B,1)
    Updater_65395172049297_kernel<<<GRID, BLOCK, 0, stream>>>(x, W, bv, n0v, out);
}

// Round 11
// 103.325 us; speedup vs baseline: 1.2323x; 1.2323x over previous
//
#include <hip/hip_runtime.h>

// Updater: B=4194304 sequential scan, 3 independent scalar recurrences
//   net' = sigmoid(10*(net + u - 0.5)), u = W*x + b, pred = x . net'
// Chunked-scan parallelization with certified warm-up (monotone map ->
// trajectories from 0 and 1 bracket the truth; dual-trajectory warm-up with
// wave-uniform early exit; geometric global backoff, rare, exact at net0).
//
// R11 = R10 with the spill fixed. R10 counters: FETCH 48MB = exactly unique
// (wave-contiguous load + LDS transpose WORKS), but launch_bounds(256,4)
// capped VGPR at 64 -> fx[48]+staging spilled (WRITE 84MB vs 17 ideal,
// kernel latency-bound on scratch at 58us). Third instance of the pattern:
// tight wave-min bounds shrink the register budget below the live set
// ((256,8)->32, (256,4)->64). Live set here ~110 regs; (256,2) leaves
// headroom to ~128 -> no spill, and HW still runs 4 waves/SIMD when the
// allocation lands <=128.
// Structure (proven pieces):
//  - wave window (12KB) loaded as 12 wave-contiguous dwordx4/lane in 4
//    quarters, double-buffered through per-wave LDS (2 x 3328B);
//    transpose write (region QW=52 words/lane), lane ds_read_b128 its own
//    12 float4 -> fx[48]. Wave-private: no __syncthreads (in-order DS).
//  - CHUNK=16, GRID=1024 = 4 blocks/CU single round, 4 waves/SIMD.
//  - WARM=32 via distance-2/1 bpermutes; lanes 0,1 from per-wave wbuf;
//    block0/wave0 rolled special path; certified geometric backoff.

#if __has_builtin(__builtin_amdgcn_exp2f)
#define EXP2F(v) __builtin_amdgcn_exp2f(v)
#else
#define EXP2F(v) __expf(0.6931471805599453f * (v))
#endif

namespace {
constexpr int   BTOT   = 4194304;
constexpr int   CHUNK  = 16;                  // output steps per thread
constexpr int   BLOCK  = 256;
constexpr int   BSTEPS = BLOCK * CHUNK;       // 4096 steps per block
constexpr int   WARM   = 32;                  // warm-up window (steps)
constexpr int   GRID   = BTOT / BSTEPS;       // 1024 blocks
constexpr int   QW     = 52;                  // words per lane region (48+4 pad)
constexpr float KEXP   = -14.426950408889634f; // -10 * log2(e)
constexpr float EPS    = 1e-5f;
}

// sigmoid(10*(n+u-0.5)) = rcp(1 + exp2(KEXP*n + c)), c = (KEXP*W)x + KEXP*(b-.5)
#define CVALS(X0_, X1_, X2_)                                                   \
  const float c0 = fmaf(kw00, (X0_), fmaf(kw01, (X1_), fmaf(kw02, (X2_), kb0))); \
  const float c1 = fmaf(kw10, (X0_), fmaf(kw11, (X1_), fmaf(kw12, (X2_), kb1))); \
  const float c2 = fmaf(kw20, (X0_), fmaf(kw21, (X1_), fmaf(kw22, (X2_), kb2)));

#define SIG(N, C) __builtin_amdgcn_rcpf(1.0f + EXP2F(fmaf(KEXP, (N), (C))))

#define PULL(VAL_, AD_) \
  __int_as_float(__builtin_amdgcn_ds_bpermute((AD_), __float_as_int(VAL_)))

// warm-step S_ (compile-time): s<16 -> owner lane-2 (pa2); s>=16 -> lane-1
// (pa1). Boundary: lane0 all s -> wbuf[s]; lane1 s<16 -> wbuf[s+16].
#define FETCH1(S_, XD0, XD1, XD2)                                              \
  if ((S_) < 16) {                                                             \
    XD0 = PULL(fx[3 * (S_) + 0], pa2);                                         \
    XD1 = PULL(fx[3 * (S_) + 1], pa2);                                         \
    XD2 = PULL(fx[3 * (S_) + 2], pa2);                                         \
    if (lane < 2) {                                                            \
      const float4 wv_ = wb[(S_) + (lane << 4)];                               \
      XD0 = wv_.x; XD1 = wv_.y; XD2 = wv_.z;                                   \
    }                                                                          \
  } else {                                                                     \
    XD0 = PULL(fx[3 * ((S_) - 16) + 0], pa1);                                  \
    XD1 = PULL(fx[3 * ((S_) - 16) + 1], pa1);                                  \
    XD2 = PULL(fx[3 * ((S_) - 16) + 2], pa1);                                  \
    if (lane < 1) {                                                            \
      const float4 wv_ = wb[(S_)];                                             \
      XD0 = wv_.x; XD1 = wv_.y; XD2 = wv_.z;                                   \
    }                                                                          \
  }

// dual-trajectory (bracket) step
#define DSTEP(X0_, X1_, X2_)                                                   \
  {                                                                            \
    CVALS(X0_, X1_, X2_)                                                       \
    lo0 = SIG(lo0, c0); hi0 = SIG(hi0, c0);                                    \
    lo1 = SIG(lo1, c1); hi1 = SIG(hi1, c1);                                    \
    lo2 = SIG(lo2, c2); hi2 = SIG(hi2, c2);                                    \
  }

// single-trajectory step
#define SSTEP(X0_, X1_, X2_)                                                   \
  {                                                                            \
    CVALS(X0_, X1_, X2_)                                                       \
    m0 = SIG(m0, c0); m1 = SIG(m1, c1); m2 = SIG(m2, c2);                      \
  }

// warm batch: 4 steps; fetches hoisted above the wave-uniform branch
#define WBATCH(B_)                                                             \
  {                                                                            \
    float X00,X01,X02,X10,X11,X12,X20,X21,X22,X30,X31,X32;                     \
    FETCH1(4*(B_)+0, X00, X01, X02)                                            \
    FETCH1(4*(B_)+1, X10, X11, X12)                                            \
    FETCH1(4*(B_)+2, X20, X21, X22)                                            \
    FETCH1(4*(B_)+3, X30, X31, X32)                                            \
    if (!single) {                                                             \
      DSTEP(X00, X01, X02) DSTEP(X10, X11, X12)                                \
      DSTEP(X20, X21, X22) DSTEP(X30, X31, X32)                                \
      conv = ((hi0 - lo0) < EPS) & ((hi1 - lo1) < EPS) & ((hi2 - lo2) < EPS);  \
      if (__all(conv)) {                                                       \
        m0 = 0.5f * (lo0 + hi0); m1 = 0.5f * (lo1 + hi1);                      \
        m2 = 0.5f * (lo2 + hi2);                                               \
        single = true;                                                         \
      }                                                                        \
    } else {                                                                   \
      SSTEP(X00, X01, X02) SSTEP(X10, X11, X12)                                \
      SSTEP(X20, X21, X22) SSTEP(X30, X31, X32)                                \
    }                                                                          \
  }

// main step: advance + pred (x from registers)
#define MS(P_, X0_, X1_, X2_)                                                  \
  {                                                                            \
    CVALS(X0_, X1_, X2_)                                                       \
    m0 = SIG(m0, c0); m1 = SIG(m1, c1); m2 = SIG(m2, c2);                      \
    P_ = fmaf((X0_), m0, fmaf((X1_), m1, (X2_) * m2));                         \
  }

// LDS float4 store / lane-region read
#define STW(P_, O_, V_) *reinterpret_cast<float4*>((P_) + (O_)) = (V_);
#define RDQ(P_)                                                                \
  _Pragma("unroll")                                                            \
  for (int j = 0; j < 12; ++j) {                                               \
    const float4 v = *reinterpret_cast<const float4*>((P_) + rb + 4 * j);      \
    fx[4 * j + 0] = v.x; fx[4 * j + 1] = v.y;                                  \
    fx[4 * j + 2] = v.z; fx[4 * j + 3] = v.w;                                  \
  }

__global__ __launch_bounds__(BLOCK, 2) void Updater_65395172049297_kernel(
    const float* __restrict__ x, const float* __restrict__ W,
    const float* __restrict__ bv, const float* __restrict__ n0v,
    float* __restrict__ out)
{
    __shared__ float  qbuf[BLOCK / 64][2][16 * QW];  // 4w x 2 x 3328B = 26.6KB
    __shared__ float4 wbuf[BLOCK / 64][WARM];        // 4w x 32 x 16B  =  2KB

    const float kw00 = KEXP * W[0], kw01 = KEXP * W[1], kw02 = KEXP * W[2];
    const float kw10 = KEXP * W[3], kw11 = KEXP * W[4], kw12 = KEXP * W[5];
    const float kw20 = KEXP * W[6], kw21 = KEXP * W[7], kw22 = KEXP * W[8];
    const float kb0 = KEXP * (bv[0] - 0.5f);
    const float kb1 = KEXP * (bv[1] - 0.5f);
    const float kb2 = KEXP * (bv[2] - 0.5f);
    const float n00 = n0v[0], n01 = n0v[1], n02 = n0v[2];

    const int  lane  = threadIdx.x & 63;
    const int  w     = threadIdx.x >> 6;
    const long S     = (long)blockIdx.x * BSTEPS;
    const long Wb    = S + (long)w * (64 * CHUNK);       // wave base step
    const long start = Wb + (long)lane * CHUNK;
    const int  pa1   = ((lane >= 1) ? (lane - 1) : 0) << 2;  // bpermute addrs
    const int  pa2   = ((lane >= 2) ? (lane - 2) : 0) << 2;
    const float4* wb = wbuf[w];

    // ---- boundary window load first (lanes 0..31, 1 scalar-triple each) ----
    float4 wv;
    if (lane < WARM) {
        long sstep = Wb - WARM + lane;
        if (sstep < 0) sstep = 0;        // block0/wave0 uses the special path
        const float* xp = x + 3 * sstep;
        wv = make_float4(xp[0], xp[1], xp[2], 0.0f);
    }

    // ---- wave-contiguous gather + LDS transpose -> fx[48] ----
    // wave window = 768 float4; load pattern xw[64*i + lane] = 1KB/instr.
    const float4* xw = reinterpret_cast<const float4*>(x) +
                       ((long)blockIdx.x * 3072 + (long)w * 768);
    // transpose write addrs: quarter-local g = 64i+lane -> region g/12,
    // slot g%12 -> word (g/12)*QW + (g%12)*4
    const int g0  = lane, g1 = 64 + lane, g2 = 128 + lane;
    const int wa0 = (g0 / 12) * QW + (g0 % 12) * 4;
    const int wa1 = (g1 / 12) * QW + (g1 % 12) * 4;
    const int wa2 = (g2 / 12) * QW + (g2 % 12) * 4;
    float* A  = qbuf[w][0];
    float* Bf = qbuf[w][1];
    const int myq = lane >> 4;           // which quarter holds my chunk
    const int rb  = (lane & 15) * QW;    // my region base (words)

    float fx[48];
    {
        float4 r0 = xw[g0],       r1 = xw[g1],       r2 = xw[g2];        // q0
        float4 s0 = xw[192 + g0], s1 = xw[192 + g1], s2 = xw[192 + g2];  // q1
        STW(A, wa0, r0) STW(A, wa1, r1) STW(A, wa2, r2)                  // q0->A
        if (myq == 0) { RDQ(A) }                                         // 0-15
        r0 = xw[384 + g0]; r1 = xw[384 + g1]; r2 = xw[384 + g2];         // q2
        STW(Bf, wa0, s0) STW(Bf, wa1, s1) STW(Bf, wa2, s2)               // q1->B
        if (myq == 1) { RDQ(Bf) }                                        // 16-31
        s0 = xw[576 + g0]; s1 = xw[576 + g1]; s2 = xw[576 + g2];         // q3
        STW(A, wa0, r0) STW(A, wa1, r1) STW(A, wa2, r2)                  // q2->A
        if (myq == 2) { RDQ(A) }                                         // 32-47
        STW(Bf, wa0, s0) STW(Bf, wa1, s1) STW(Bf, wa2, s2)               // q3->B
        if (myq == 3) { RDQ(Bf) }                                        // 48-63
    }

    // wave-private wbuf publish (in-order DS pipe; no __syncthreads)
    if (lane < WARM) wbuf[w][lane] = wv;

    const bool exact   = (start <= (long)WARM);   // block0/wave0 lanes 0,1,2
    const int  smin    = exact ? (int)(WARM - (int)start) : 0;
    const bool special = (blockIdx.x == 0) && (w == 0);

    float lo0, lo1, lo2, hi0, hi1, hi2;
    if (exact) { lo0 = hi0 = n00; lo1 = hi1 = n01; lo2 = hi2 = n02; }
    else       { lo0 = lo1 = lo2 = 0.0f; hi0 = hi1 = hi2 = 1.0f; }

    bool  conv = false, single = false;
    float m0 = n00, m1 = n01, m2 = n02;

    if (special) {
        // ONE wave in the grid: rolled warm-up straight from global x.
        for (int s = 0; s < WARM; ++s) {
            if (s >= smin) {
                const long as_ = start - WARM + s;   // >= 0 when s >= smin
                const float X0 = x[3 * as_], X1 = x[3 * as_ + 1], X2 = x[3 * as_ + 2];
                DSTEP(X0, X1, X2)
            }
        }
        conv = ((hi0 - lo0) < EPS) & ((hi1 - lo1) < EPS) & ((hi2 - lo2) < EPS);
        if (__all(conv)) {
            m0 = 0.5f * (lo0 + hi0); m1 = 0.5f * (lo1 + hi1); m2 = 0.5f * (lo2 + hi2);
            single = true;
        }
    } else {
        WBATCH(0) WBATCH(1) WBATCH(2) WBATCH(3)
        WBATCH(4) WBATCH(5) WBATCH(6) WBATCH(7)
    }

    if (!single) {
        // rare certified backoff: extend window 4x per attempt (global x)
        for (int at = 1; at < 10 && !conv; ++at) {
            long wl2 = (long)WARM << (2 * at);
            long bgn = start - wl2;
            bool ex2 = (bgn <= 0);
            if (ex2) bgn = 0;
            if (ex2) { lo0 = hi0 = n00; lo1 = hi1 = n01; lo2 = hi2 = n02; }
            else     { lo0 = lo1 = lo2 = 0.0f; hi0 = hi1 = hi2 = 1.0f; }
            const float4* bp = reinterpret_cast<const float4*>(x + 3 * bgn);
            const long ng = (start - bgn) >> 2;   // groups of 4 steps
            for (long q = 0; q < ng; ++q) {
                const float4 A4 = bp[3 * q], B4 = bp[3 * q + 1], C4 = bp[3 * q + 2];
                DSTEP(A4.x, A4.y, A4.z)
                DSTEP(A4.w, B4.x, B4.y)
                DSTEP(B4.z, B4.w, C4.x)
                DSTEP(C4.y, C4.z, C4.w)
            }
            conv = ex2 || (((hi0 - lo0) < EPS) & ((hi1 - lo1) < EPS) &
                           ((hi2 - lo2) < EPS));
        }
        m0 = 0.5f * (lo0 + hi0); m1 = 0.5f * (lo1 + hi1); m2 = 0.5f * (lo2 + hi2);
    }

    // ---- main chunk: 16 steps from registers, 4 float4 stores ----
    float4* op = reinterpret_cast<float4*>(out + start);
#pragma unroll
    for (int q = 0; q < 4; ++q) {
        float p0, p1, p2, p3;
        MS(p0, fx[12 * q + 0], fx[12 * q + 1],  fx[12 * q + 2]);
        MS(p1, fx[12 * q + 3], fx[12 * q + 4],  fx[12 * q + 5]);
        MS(p2, fx[12 * q + 6], fx[12 * q + 7],  fx[12 * q + 8]);
        MS(p3, fx[12 * q + 9], fx[12 * q + 10], fx[12 * q + 11]);
        op[q] = make_float4(p0, p1, p2, p3);
    }
}

extern "C" void kernel_launch(void* const* d_in, const int* in_sizes, int n_in,
                              void* d_out, int out_size, void* d_ws, size_t ws_size,
                              hipStream_t stream) {
    const float* x   = (const float*)d_in[0];   // (B,1,3)
    const float* W   = (const float*)d_in[1];   // (3,3)
    const float* bv  = (const float*)d_in[2];   // (3,)
    const float* n0v = (const float*)d_in[3];   // (3,1)
    float*       out = (float*)d_out;           // (B,1)
    Updater_65395172049297_kernel<<<GRID, BLOCK, 0, stream>>>(x, W, bv, n0v, out);
}

// Round 12
// 101.020 us; speedup vs baseline: 1.2605x; 1.0228x over previous
//
#include <hip/hip_runtime.h>

// Updater: B=4194304 sequential scan, 3 independent scalar recurrences
//   net' = sigmoid(10*(net + u - 0.5)), u = W*x + b, pred = x . net'
// Chunked-scan parallelization with certified warm-up (monotone map ->
// trajectories from 0 and 1 bracket the truth; dual-trajectory warm-up with
// wave-uniform early exit; geometric global backoff, rare, exact at net0).
//
// R12 = R7's residency x R11's load shape. Evidence: single-round configs
// cost VALU-issue + ~23us ~= 67MB/2.7TB/s; fills hit 6.3 TB/s. R7
// (guaranteed single round, per-lane gather: 24 loads x 64 lines = 4x
// line amplification) = 27.6us. R11 (wave-contiguous, FETCH 48MB proven
// unique) may have run 2 rounds (VGPR>128 under (256,2)). This round
// removes the ambiguity:
//  - CHUNK=32, GRID=512, fx[96], __launch_bounds__(256,2): ~170 VGPR,
//    no spill (R7-proven), 2 waves/SIMD needed = 2 waves/SIMD resident
//    -> SINGLE ROUND GUARANTEED (LDS 53KB -> 2 blocks/CU).
//  - fx gather is wave-contiguous: 24 dwordx4/lane in 4 quarter-phases
//    (6 loads each), double-buffered through a per-wave LDS transpose
//    (regions QW=100 words: read base 4*(lane&15) mod 32 -> 2 lanes/bank
//    = conflict-free b128 reads). 16 fully-used lines per load instr.
//  - warm/backoff/store = R7 verbatim (distance-1 bpermute, lane0 wbuf,
//    start==0 overwrite, certified geometric backoff).
// Predicted: FETCH ~52MB, WRITE ~17MB, kernel ~16-19us. If ~27us with
// clean counters -> read wall is structural -> ROOFLINE next round.

#if __has_builtin(__builtin_amdgcn_exp2f)
#define EXP2F(v) __builtin_amdgcn_exp2f(v)
#else
#define EXP2F(v) __expf(0.6931471805599453f * (v))
#endif

namespace {
constexpr int   BTOT   = 4194304;
constexpr int   CHUNK  = 32;                  // output steps per thread
constexpr int   BLOCK  = 256;
constexpr int   BSTEPS = BLOCK * CHUNK;       // 8192 steps per block
constexpr int   WARM   = 32;                  // warm-up window (steps)
constexpr int   GRID   = BTOT / BSTEPS;       // 512 blocks
constexpr int   QW     = 100;                 // words per lane region (96+4 pad)
constexpr float KEXP   = -14.426950408889634f; // -10 * log2(e)
constexpr float EPS    = 1e-5f;
}

// sigmoid(10*(n+u-0.5)) = rcp(1 + exp2(KEXP*n + c)), c = (KEXP*W)x + KEXP*(b-.5)
#define CVALS(X0_, X1_, X2_)                                                   \
  const float c0 = fmaf(kw00, (X0_), fmaf(kw01, (X1_), fmaf(kw02, (X2_), kb0))); \
  const float c1 = fmaf(kw10, (X0_), fmaf(kw11, (X1_), fmaf(kw12, (X2_), kb1))); \
  const float c2 = fmaf(kw20, (X0_), fmaf(kw21, (X1_), fmaf(kw22, (X2_), kb2)));

#define SIG(N, C) __builtin_amdgcn_rcpf(1.0f + EXP2F(fmaf(KEXP, (N), (C))))

// pull lane-1's register (addr pa1 precomputed); lane 0 overridden via wbuf
#define PULL(VAL_) \
  __int_as_float(__builtin_amdgcn_ds_bpermute(pa1, __float_as_int(VAL_)))

// warm-step S_ (compile-time): x = lane-1's fx[3S..3S+2]; lane0 from wbuf
#define FETCH1(S_, XD0, XD1, XD2)                                              \
  XD0 = PULL(fx[3 * (S_) + 0]);                                                \
  XD1 = PULL(fx[3 * (S_) + 1]);                                                \
  XD2 = PULL(fx[3 * (S_) + 2]);                                                \
  if (lane == 0) {                                                             \
    const float4 wv_ = wb[(S_)];                                               \
    XD0 = wv_.x; XD1 = wv_.y; XD2 = wv_.z;                                     \
  }

// dual-trajectory (bracket) step
#define DSTEP(X0_, X1_, X2_)                                                   \
  {                                                                            \
    CVALS(X0_, X1_, X2_)                                                       \
    lo0 = SIG(lo0, c0); hi0 = SIG(hi0, c0);                                    \
    lo1 = SIG(lo1, c1); hi1 = SIG(hi1, c1);                                    \
    lo2 = SIG(lo2, c2); hi2 = SIG(hi2, c2);                                    \
  }

// single-trajectory step
#define SSTEP(X0_, X1_, X2_)                                                   \
  {                                                                            \
    CVALS(X0_, X1_, X2_)                                                       \
    m0 = SIG(m0, c0); m1 = SIG(m1, c1); m2 = SIG(m2, c2);                      \
  }

// warm batch: 4 steps; fetches hoisted above the wave-uniform branch
#define WBATCH(B_)                                                             \
  {                                                                            \
    float X00,X01,X02,X10,X11,X12,X20,X21,X22,X30,X31,X32;                     \
    FETCH1(4*(B_)+0, X00, X01, X02)                                            \
    FETCH1(4*(B_)+1, X10, X11, X12)                                            \
    FETCH1(4*(B_)+2, X20, X21, X22)                                            \
    FETCH1(4*(B_)+3, X30, X31, X32)                                            \
    if (!single) {                                                             \
      DSTEP(X00, X01, X02) DSTEP(X10, X11, X12)                                \
      DSTEP(X20, X21, X22) DSTEP(X30, X31, X32)                                \
      conv = ((hi0 - lo0) < EPS) & ((hi1 - lo1) < EPS) & ((hi2 - lo2) < EPS);  \
      if (__all(conv)) {                                                       \
        m0 = 0.5f * (lo0 + hi0); m1 = 0.5f * (lo1 + hi1);                      \
        m2 = 0.5f * (lo2 + hi2);                                               \
        single = true;                                                         \
      }                                                                        \
    } else {                                                                   \
      SSTEP(X00, X01, X02) SSTEP(X10, X11, X12)                                \
      SSTEP(X20, X21, X22) SSTEP(X30, X31, X32)                                \
    }                                                                          \
  }

// main step: advance + pred (x from registers)
#define MS(P_, X0_, X1_, X2_)                                                  \
  {                                                                            \
    CVALS(X0_, X1_, X2_)                                                       \
    m0 = SIG(m0, c0); m1 = SIG(m1, c1); m2 = SIG(m2, c2);                      \
    P_ = fmaf((X0_), m0, fmaf((X1_), m1, (X2_) * m2));                         \
  }

// LDS float4 store / lane-region read of one quarter (24 float4 -> fx)
#define STW(P_, O_, V_) *reinterpret_cast<float4*>((P_) + (O_)) = (V_);
#define RDQ(P_)                                                                \
  _Pragma("unroll")                                                            \
  for (int j = 0; j < 24; ++j) {                                               \
    const float4 v = *reinterpret_cast<const float4*>((P_) + rb + 4 * j);      \
    fx[4 * j + 0] = v.x; fx[4 * j + 1] = v.y;                                  \
    fx[4 * j + 2] = v.z; fx[4 * j + 3] = v.w;                                  \
  }
// stage one quarter (6 wave-contiguous dwordx4) into registers
#define LDQ(Q_, R0_, R1_, R2_, R3_, R4_, R5_)                                  \
  R0_ = xw[384 * (Q_)       + lane]; R1_ = xw[384 * (Q_) +  64 + lane];        \
  R2_ = xw[384 * (Q_) + 128 + lane]; R3_ = xw[384 * (Q_) + 192 + lane];        \
  R4_ = xw[384 * (Q_) + 256 + lane]; R5_ = xw[384 * (Q_) + 320 + lane];
#define WRQ(P_, R0_, R1_, R2_, R3_, R4_, R5_)                                  \
  STW(P_, wa0, R0_) STW(P_, wa1, R1_) STW(P_, wa2, R2_)                        \
  STW(P_, wa3, R3_) STW(P_, wa4, R4_) STW(P_, wa5, R5_)

__global__ __launch_bounds__(BLOCK, 2) void Updater_65395172049297_kernel(
    const float* __restrict__ x, const float* __restrict__ W,
    const float* __restrict__ bv, const float* __restrict__ n0v,
    float* __restrict__ out)
{
    __shared__ float  qbuf[BLOCK / 64][2][16 * QW];  // 4w x 2 x 6400B = 51.2KB
    __shared__ float4 wbuf[BLOCK / 64][WARM];        // 4w x 32 x 16B  =  2KB

    const float kw00 = KEXP * W[0], kw01 = KEXP * W[1], kw02 = KEXP * W[2];
    const float kw10 = KEXP * W[3], kw11 = KEXP * W[4], kw12 = KEXP * W[5];
    const float kw20 = KEXP * W[6], kw21 = KEXP * W[7], kw22 = KEXP * W[8];
    const float kb0 = KEXP * (bv[0] - 0.5f);
    const float kb1 = KEXP * (bv[1] - 0.5f);
    const float kb2 = KEXP * (bv[2] - 0.5f);
    const float n00 = n0v[0], n01 = n0v[1], n02 = n0v[2];

    const int  lane  = threadIdx.x & 63;
    const int  w     = threadIdx.x >> 6;
    const long S     = (long)blockIdx.x * BSTEPS;
    const long Wb    = S + (long)w * (64 * CHUNK);       // wave base step
    const long start = Wb + (long)lane * CHUNK;
    const int  pa1   = ((lane >= 1) ? (lane - 1) : 0) << 2;
    const float4* wb = wbuf[w];

    // ---- boundary window load first (lanes 0..31, 1 scalar-triple each) ----
    float4 wv;
    if (lane < WARM) {
        long sstep = Wb - WARM + lane;
        if (sstep < 0) sstep = 0;   // block0/wave0 lane0: consumed only by
                                    // the overwritten start==0 trajectory
        const float* xp = x + 3 * sstep;
        wv = make_float4(xp[0], xp[1], xp[2], 0.0f);
    }

    // ---- wave-contiguous gather + LDS transpose -> fx[96] ----
    // wave window = 1536 float4; pattern xw[64*i + lane] = 1KB per instr
    // (16 fully-used 64B lines). 4 quarter-phases of 384 float4 each,
    // double-buffered A/B. Quarter q serves consumer lanes [16q,16q+16):
    // region r = g/24 (g = quarter-local slot), slot g%24, word r*QW+4*(g%24).
    const float4* xw = reinterpret_cast<const float4*>(x) +
                       ((long)blockIdx.x * 6144 + (long)w * 1536);
    const int g0 = lane, g1 = 64 + lane, g2 = 128 + lane;
    const int g3 = 192 + lane, g4 = 256 + lane, g5 = 320 + lane;
    const int wa0 = (g0 / 24) * QW + (g0 % 24) * 4;
    const int wa1 = (g1 / 24) * QW + (g1 % 24) * 4;
    const int wa2 = (g2 / 24) * QW + (g2 % 24) * 4;
    const int wa3 = (g3 / 24) * QW + (g3 % 24) * 4;
    const int wa4 = (g4 / 24) * QW + (g4 % 24) * 4;
    const int wa5 = (g5 / 24) * QW + (g5 % 24) * 4;
    float* A  = qbuf[w][0];
    float* Bf = qbuf[w][1];
    const int myq = lane >> 4;           // which quarter holds my chunk
    const int rb  = (lane & 15) * QW;    // my region base (words)

    float fx[96];
    {
        float4 r0, r1, r2, r3, r4, r5, s0, s1, s2, s3, s4, s5;
        LDQ(0, r0, r1, r2, r3, r4, r5)                    // q0 in flight
        LDQ(1, s0, s1, s2, s3, s4, s5)                    // q1 in flight
        WRQ(A, r0, r1, r2, r3, r4, r5)                    // q0 -> A
        if (myq == 0) { RDQ(A) }                          // lanes 0-15
        LDQ(2, r0, r1, r2, r3, r4, r5)                    // q2 in flight
        WRQ(Bf, s0, s1, s2, s3, s4, s5)                   // q1 -> B
        if (myq == 1) { RDQ(Bf) }                         // lanes 16-31
        LDQ(3, s0, s1, s2, s3, s4, s5)                    // q3 in flight
        WRQ(A, r0, r1, r2, r3, r4, r5)                    // q2 -> A
        if (myq == 2) { RDQ(A) }                          // lanes 32-47
        WRQ(Bf, s0, s1, s2, s3, s4, s5)                   // q3 -> B
        if (myq == 3) { RDQ(Bf) }                         // lanes 48-63
    }

    // wave-private wbuf publish (in-order DS pipe; no __syncthreads)
    if (lane < WARM) wbuf[w][lane] = wv;

    // exact-start lanes: block0/wave0 lanes 0 (start=0) and 1 (start=32).
    // Width-0 bracket -> identical lo/hi updates -> conv stays true; lane0's
    // (garbage-x) trajectory is overwritten with net0 after the warm-up.
    const bool exact = (start <= (long)WARM);
    float lo0, lo1, lo2, hi0, hi1, hi2;
    if (exact) { lo0 = hi0 = n00; lo1 = hi1 = n01; lo2 = hi2 = n02; }
    else       { lo0 = lo1 = lo2 = 0.0f; hi0 = hi1 = hi2 = 1.0f; }

    bool  conv = false, single = false;
    float m0 = n00, m1 = n01, m2 = n02;

    WBATCH(0) WBATCH(1) WBATCH(2) WBATCH(3)
    WBATCH(4) WBATCH(5) WBATCH(6) WBATCH(7)

    if (!single) {
        // rare certified backoff: extend window 4x per attempt (global x)
        for (int at = 1; at < 10 && !conv; ++at) {
            long wl2 = (long)WARM << (2 * at);
            long bgn = start - wl2;
            bool ex2 = (bgn <= 0);
            if (ex2) bgn = 0;
            if (ex2) { lo0 = hi0 = n00; lo1 = hi1 = n01; lo2 = hi2 = n02; }
            else     { lo0 = lo1 = lo2 = 0.0f; hi0 = hi1 = hi2 = 1.0f; }
            const float4* bp = reinterpret_cast<const float4*>(x + 3 * bgn);
            const long ng = (start - bgn) >> 2;   // groups of 4 steps
            for (long q = 0; q < ng; ++q) {
                const float4 A4 = bp[3 * q], B4 = bp[3 * q + 1], C4 = bp[3 * q + 2];
                DSTEP(A4.x, A4.y, A4.z)
                DSTEP(A4.w, B4.x, B4.y)
                DSTEP(B4.z, B4.w, C4.x)
                DSTEP(C4.y, C4.z, C4.w)
            }
            conv = ex2 || (((hi0 - lo0) < EPS) & ((hi1 - lo1) < EPS) &
                           ((hi2 - lo2) < EPS));
        }
        m0 = 0.5f * (lo0 + hi0); m1 = 0.5f * (lo1 + hi1); m2 = 0.5f * (lo2 + hi2);
    }

    // the single thread whose whole warm window is out-of-range: exact net0
    if (start == 0) { m0 = n00; m1 = n01; m2 = n02; }

    // ---- main chunk: 32 steps from registers, 8 float4 stores ----
    float4* op = reinterpret_cast<float4*>(out + start);
#pragma unroll
    for (int q = 0; q < 8; ++q) {
        float p0, p1, p2, p3;
        MS(p0, fx[12 * q + 0], fx[12 * q + 1],  fx[12 * q + 2]);
        MS(p1, fx[12 * q + 3], fx[12 * q + 4],  fx[12 * q + 5]);
        MS(p2, fx[12 * q + 6], fx[12 * q + 7],  fx[12 * q + 8]);
        MS(p3, fx[12 * q + 9], fx[12 * q + 10], fx[12 * q + 11]);
        op[q] = make_float4(p0, p1, p2, p3);
    }
}

extern "C" void kernel_launch(void* const* d_in, const int* in_sizes, int n_in,
                              void* d_out, int out_size, void* d_ws, size_t ws_size,
                              hipStream_t stream) {
    const float* x   = (const float*)d_in[0];   // (B,1,3)
    const float* W   = (const float*)d_in[1];   // (3,3)
    const float* bv  = (const float*)d_in[2];   // (3,)
    const float* n0v = (const float*)d_in[3];   // (3,1)
    float*       out = (float*)d_out;           // (B,1)
    Updater_65395172049297_kernel<<<GRID, BLOCK, 0, stream>>>(x, W, bv, n0v, out);
}